// Round 4
// baseline (602.930 us; speedup 1.0000x reference)
//
#include <hip/hip_runtime.h>
#include <hip/hip_bf16.h>

// ===== INSTRUMENTATION ROUND: each kernel body repeats REP times (idempotent,
// pure-function bodies) so per-kernel durations/counters surface in the top-5
// dispatch view. dur_us this round is ~REP x inflated by design. =====
#define REP 16

#define DIM 256
#define NP 2048
#define NH 8
#define BATCH 2
#define DH 32

typedef __attribute__((ext_vector_type(8))) short bshort8;
typedef __attribute__((ext_vector_type(4))) short bshort4;
typedef __attribute__((ext_vector_type(4))) float f32x4;

#define LOG2E 1.44269504f
// (Dh^-0.5) * log2(e), folded into WT rows 0..255 (W_q) at prep time
#define QSCALE (0.17677669529663687f * LOG2E)

union U16B { uint4 u; bshort8 s8; bshort4 s4x[2]; __hip_bfloat16 h[8]; };
union U8B  { uint2 u; bshort4 s4; __hip_bfloat16 h[4]; };

__device__ __forceinline__ float fexp2(float x) { return __builtin_amdgcn_exp2f(x); }
// pack two fp32 -> two bf16 (truncation) in one v_perm
__device__ __forceinline__ unsigned packbf(float hi, float lo) {
    return __builtin_amdgcn_perm(__float_as_uint(hi), __float_as_uint(lo), 0x07060302u);
}
// async global->LDS, 16B per lane. LDS dest = wave-uniform base + lane*16.
__device__ __forceinline__ void gl16(const void* g, void* l) {
    __builtin_amdgcn_global_load_lds(
        (const __attribute__((address_space(1))) void*)g,
        (__attribute__((address_space(3))) void*)l, 16, 0, 0);
}
// LDS tile addressing: 64 rows x 256 elems, XOR-swizzled 16B granules.
__device__ __forceinline__ int lds_addr(int row, int colg) {
    return row * 256 + (((colg ^ (row & 7)) & 31) << 3);
}

// ============ kernel 0: prep — W transpose -> bf16 WT[1024][256]; x -> bf16 ==
__global__ __launch_bounds__(256) void prep_kernel(
    const float* __restrict__ Wqk,
    const float* __restrict__ Wv,
    const float* __restrict__ Wproj,
    const float* __restrict__ x,
    __hip_bfloat16* __restrict__ WT,
    __hip_bfloat16* __restrict__ xb) {
    const int t = threadIdx.x;
    const int blk = blockIdx.x;
    __shared__ float ts[64][65];
    for (int rep = 0; rep < REP; ++rep) {
        if (blk >= 64) {
            const int base = (blk - 64) * 256 + t;
#pragma unroll
            for (int i = 0; i < 16; i++) {
                const int idx = base + i * 16384;
                float4 f = *(const float4*)(x + (size_t)idx * 4);
                U8B a;
                a.h[0] = __float2bfloat16(f.x); a.h[1] = __float2bfloat16(f.y);
                a.h[2] = __float2bfloat16(f.z); a.h[3] = __float2bfloat16(f.w);
                *(uint2*)(xb + (size_t)idx * 4) = a.u;
            }
        } else {
            const int ct = blk >> 2, k0 = (blk & 3) * 64;
            const int c0 = ct * 64;
            const float* src; int ldw, cs0; float scl = 1.0f;
            if (ct < 8)       { src = Wqk;   ldw = 512; cs0 = c0;      if (ct < 4) scl = QSCALE; }
            else if (ct < 12) { src = Wv;    ldw = 256; cs0 = c0 - 512; }
            else              { src = Wproj; ldw = 256; cs0 = c0 - 768; }
            const int cc = t & 63, tq = t >> 6;
#pragma unroll
            for (int j = 0; j < 16; j++) {
                int kk = tq * 16 + j;
                ts[kk][cc] = src[(size_t)(k0 + kk) * ldw + cs0 + cc];
            }
            __syncthreads();
            const int kk2 = t & 63;
#pragma unroll
            for (int j = 0; j < 16; j++) {
                int cc2 = tq * 16 + j;
                WT[(size_t)(c0 + cc2) * 256 + k0 + kk2] = __float2bfloat16(ts[kk2][cc2] * scl);
            }
        }
        __syncthreads();
    }
}

// ============ kernel 1: QKV projection — global_load_lds staged MFMA GEMM ===
__global__ __launch_bounds__(256) void qkv_mfma(
    const __hip_bfloat16* __restrict__ xb,
    const __hip_bfloat16* __restrict__ WT,
    __hip_bfloat16* __restrict__ qT,
    __hip_bfloat16* __restrict__ k,
    __hip_bfloat16* __restrict__ vT) {
    __shared__ __align__(16) __hip_bfloat16 As[64 * 256];
    __shared__ __align__(16) __hip_bfloat16 Bs[64 * 256];
    const int t = threadIdx.x, lane = t & 63, wvid = t >> 6;
    const int l15 = lane & 15, l4 = lane >> 4;
    const int m0 = blockIdx.x * 64;
    const int nb0 = blockIdx.y * 64;
    const int nc = nb0 + wvid * 16 + l15;
    const int lrow = lane >> 5, lcg = lane & 31;

    for (int rep = 0; rep < REP; ++rep) {
#pragma unroll
        for (int j = 0; j < 8; j++) {
            const int r0 = j * 8 + wvid * 2;
            const int row = r0 + lrow;
            const int cgs = (lcg ^ (row & 7)) & 31;
            gl16(xb + (((size_t)(m0 + row)) << 8) + cgs * 8, (char*)As + r0 * 512);
            gl16(WT + (((size_t)(nb0 + row)) << 8) + cgs * 8, (char*)Bs + r0 * 512);
        }
        __syncthreads();

        f32x4 acc[4] = {{0.f,0.f,0.f,0.f},{0.f,0.f,0.f,0.f},{0.f,0.f,0.f,0.f},{0.f,0.f,0.f,0.f}};
#pragma unroll
        for (int kk = 0; kk < 8; kk++) {
            const int colg = kk * 4 + l4;
            U16B bw; bw.u = *(const uint4*)&Bs[lds_addr(wvid * 16 + l15, colg)];
#pragma unroll
            for (int mt = 0; mt < 4; mt++) {
                U16B ax; ax.u = *(const uint4*)&As[lds_addr(mt * 16 + l15, colg)];
                acc[mt] = __builtin_amdgcn_mfma_f32_16x16x32_bf16(ax.s8, bw.s8, acc[mt], 0, 0, 0);
            }
        }

        if (nb0 < 256) {             // qT[(b*256+c)][token], 8B stores (QSCALE in WT)
            const int b = m0 >> 11;
#pragma unroll
            for (int mt = 0; mt < 4; mt++) {
                int tokn = (m0 & (NP - 1)) + mt * 16 + l4 * 4;
                U8B vv;
#pragma unroll
                for (int r = 0; r < 4; r++) vv.h[r] = __float2bfloat16(acc[mt][r]);
                *(uint2*)(qT + (size_t)(b * 256 + nc) * NP + tokn) = vv.u;
            }
        } else if (nb0 < 512) {      // k[bh][n][d] (row layout needed by attn staging)
            const int c = nc - 256, h = c >> 5, d = c & 31;
#pragma unroll
            for (int mt = 0; mt < 4; mt++)
#pragma unroll
                for (int r = 0; r < 4; r++) {
                    int tok = m0 + mt * 16 + l4 * 4 + r;
                    int b = tok >> 11, n = tok & (NP - 1);
                    k[((size_t)(b * NH + h) * NP + n) * DH + d] = __float2bfloat16(acc[mt][r]);
                }
        } else {                     // vT[(b*256+c)][token], 8B stores
            const int c = nc - 512;
            const int b = m0 >> 11;
#pragma unroll
            for (int mt = 0; mt < 4; mt++) {
                int tokn = (m0 & (NP - 1)) + mt * 16 + l4 * 4;
                U8B vv;
#pragma unroll
                for (int r = 0; r < 4; r++) vv.h[r] = __float2bfloat16(acc[mt][r]);
                *(uint2*)(vT + (size_t)(b * 256 + c) * NP + tokn) = vv.u;
            }
        }
        __syncthreads();
    }
}

// ============ kernel 2: attention — LDS-staged K/V, register P, split-K =====
__global__ __launch_bounds__(512, 4) void attn_kernel(
    const __hip_bfloat16* __restrict__ qg,   // qT[bh*32+d][n]
    const __hip_bfloat16* __restrict__ kg,
    const __hip_bfloat16* __restrict__ vTg,
    const float* __restrict__ Wpos,
    const float* __restrict__ bpos,
    const float* __restrict__ gating,
    __hip_bfloat16* __restrict__ ao) {
    __shared__ __align__(16) __hip_bfloat16 Kt[2][2][64][40];
    __shared__ __align__(16) __hip_bfloat16 Vt[2][2][32][72];
    __shared__ float cmb[4][2][32][16];
    __shared__ float cls[4][2][16];

    const int t = threadIdx.x;
    const int lane = t & 63, wvid = t >> 6;
    const int l15 = lane & 15, l4 = lane >> 4;
    const int qt = wvid & 3, kh = wvid >> 2;
    const int bh = blockIdx.x >> 5, qb = blockIdx.x & 31;
    const int h = bh & (NH - 1), b = bh >> 3;
    const int q0 = qb * 64 + qt * 16;
    const int myq = q0 + l15;

    const int st_ = t & 255;
    const int kstart = kh * 1024;
    const __hip_bfloat16* kptr = kg + (size_t)bh * NP * DH + (size_t)(kstart + (st_ >> 2)) * DH + (st_ & 3) * 8;
    const __hip_bfloat16* vptr = vTg + ((size_t)bh * DH + (st_ >> 3)) * NP + kstart + (st_ & 7) * 8;

    const int vd = st_ >> 3, vs = st_ & 7;
    const int vc0 = ((2 * vs) & 3) * 16 + (vs >> 1) * 4;
    const int vc1 = ((2 * vs + 1) & 3) * 16 + (vs >> 1) * 4;

    for (int rep = 0; rep < REP; ++rep) {
        uint4 kreg = *(const uint4*)kptr;
        uint4 vreg = *(const uint4*)vptr;
        *(uint4*)&Kt[kh][0][st_ >> 2][(st_ & 3) * 8] = kreg;
        *(uint2*)&Vt[kh][0][vd][vc0] = make_uint2(vreg.x, vreg.y);
        *(uint2*)&Vt[kh][0][vd][vc1] = make_uint2(vreg.z, vreg.w);

        const float w0 = Wpos[h] * LOG2E;
        const float w1 = Wpos[NH + h] * LOG2E;
        const float g = 1.0f / (1.0f + __expf(-gating[h]));
        const float nf = (float)myq;
        const float pmax = fmaxf(0.f, fmaxf((w0 + w1) * nf, (w1 - w0) * (2047.0f - nf)));
        const float npmax = -pmax;
        const float rA = fexp2(-(w0 + w1));
        const float rB = fexp2(w1 - w0);

        U16B qv;
#pragma unroll
        for (int j = 0; j < 8; j++)
            qv.h[j] = qg[((size_t)bh * DH + l4 * 8 + j) * NP + myq];

        __syncthreads();

        f32x4 os0 = {0.f,0.f,0.f,0.f}, os1 = {0.f,0.f,0.f,0.f};
        f32x4 op0 = {0.f,0.f,0.f,0.f}, op1 = {0.f,0.f,0.f,0.f};
        float ls = 0.f, lp = 0.f;

        for (int it = 0; it < 16; ++it) {
            const int cur = it & 1, nxt = cur ^ 1;

            if (it < 15) {
                kreg = *(const uint4*)(kptr + (size_t)(it + 1) * 64 * DH);
                vreg = *(const uint4*)(vptr + (it + 1) * 64);
            }

            f32x4 st4[4];
#pragma unroll
            for (int kt = 0; kt < 4; kt++) {
                U16B kf; kf.u = *(const uint4*)&Kt[kh][cur][kt * 16 + l15][l4 * 8];
                st4[kt] = __builtin_amdgcn_mfma_f32_16x16x32_bf16(
                    kf.s8, qv.s8, (f32x4){0.f,0.f,0.f,0.f}, 0, 0, 0);
            }

            U16B va0, va1, vb0, vb1;
            {
                const __hip_bfloat16* v0 = &Vt[kh][cur][l15][l4 * 16];
                const __hip_bfloat16* v1 = &Vt[kh][cur][16 + l15][l4 * 16];
                va0.u = *(const uint4*)v0;
                va1.u = *(const uint4*)(v0 + 8);
                vb0.u = *(const uint4*)v1;
                vb1.u = *(const uint4*)(v1 + 8);
            }

            const int kb0 = kstart + it * 64;
#pragma unroll
            for (int kt = 0; kt < 4; kt++) {
                const bshort4 fa = (kt < 2) ? va0.s4x[kt & 1] : va1.s4x[kt & 1];
                const bshort4 fb = (kt < 2) ? vb0.s4x[kt & 1] : vb1.s4x[kt & 1];
                float es0 = fexp2(st4[kt][0]), es1 = fexp2(st4[kt][1]);
                float es2 = fexp2(st4[kt][2]), es3 = fexp2(st4[kt][3]);
                ls += (es0 + es1) + (es2 + es3);
                const float d0 = nf - (float)(kb0 + kt * 16 + l4 * 4);
                float ep0 = fexp2(fmaf(w1, fabsf(d0), fmaf(w0, d0, npmax)));
                float ep1 = ep0 * ((d0 >= 1.f) ? rA : rB);
                float ep2 = ep1 * ((d0 >= 2.f) ? rA : rB);
                float ep3 = ep2 * ((d0 >= 3.f) ? rA : rB);
                lp += (ep0 + ep1) + (ep2 + ep3);
                U8B pc, pp;
                pc.u.x = packbf(es1, es0); pc.u.y = packbf(es3, es2);
                pp.u.x = packbf(ep1, ep0); pp.u.y = packbf(ep3, ep2);
                os0 = __builtin_amdgcn_mfma_f32_16x16x16bf16_1k(fa, pc.s4, os0, 0, 0, 0);
                os1 = __builtin_amdgcn_mfma_f32_16x16x16bf16_1k(fb, pc.s4, os1, 0, 0, 0);
                op0 = __builtin_amdgcn_mfma_f32_16x16x16bf16_1k(fa, pp.s4, op0, 0, 0, 0);
                op1 = __builtin_amdgcn_mfma_f32_16x16x16bf16_1k(fb, pp.s4, op1, 0, 0, 0);
            }

            if (it < 15) {
                *(uint4*)&Kt[kh][nxt][st_ >> 2][(st_ & 3) * 8] = kreg;
                *(uint2*)&Vt[kh][nxt][vd][vc0] = make_uint2(vreg.x, vreg.y);
                *(uint2*)&Vt[kh][nxt][vd][vc1] = make_uint2(vreg.z, vreg.w);
            }
            __syncthreads();
        }

        ls += __shfl_xor(ls, 16, 64); ls += __shfl_xor(ls, 32, 64);
        lp += __shfl_xor(lp, 16, 64); lp += __shfl_xor(lp, 32, 64);

        if (kh == 1) {
#pragma unroll
            for (int r = 0; r < 4; r++) {
                cmb[qt][0][l4 * 4 + r][l15]      = os0[r];
                cmb[qt][0][16 + l4 * 4 + r][l15] = os1[r];
                cmb[qt][1][l4 * 4 + r][l15]      = op0[r];
                cmb[qt][1][16 + l4 * 4 + r][l15] = op1[r];
            }
            if (l4 == 0) { cls[qt][0][l15] = ls; cls[qt][1][l15] = lp; }
        }
        __syncthreads();
        if (kh == 0) {
            ls += cls[qt][0][l15]; lp += cls[qt][1][l15];
            const float cs = (1.0f - g) / ls;
            const float cp = g / lp;
            const size_t orow = ((size_t)b * NP + myq) * DIM + h * DH;
            U8B o0, o1;
#pragma unroll
            for (int r = 0; r < 4; r++) {
                o0.h[r] = __float2bfloat16(cs * (os0[r] + cmb[qt][0][l4 * 4 + r][l15]) +
                                           cp * (op0[r] + cmb[qt][1][l4 * 4 + r][l15]));
                o1.h[r] = __float2bfloat16(cs * (os1[r] + cmb[qt][0][16 + l4 * 4 + r][l15]) +
                                           cp * (op1[r] + cmb[qt][1][16 + l4 * 4 + r][l15]));
            }
            *(uint2*)(ao + orow + l4 * 4)      = o0.u;
            *(uint2*)(ao + orow + 16 + l4 * 4) = o1.u;
        }
        __syncthreads();
    }
}

// ============ kernel 3: output projection — global_load_lds staged GEMM =====
__global__ __launch_bounds__(256) void proj_mfma(
    const __hip_bfloat16* __restrict__ ao,
    const __hip_bfloat16* __restrict__ WT,
    const float* __restrict__ bias,
    float* __restrict__ out) {
    __shared__ __align__(16) __hip_bfloat16 As[64 * 256];
    __shared__ __align__(16) __hip_bfloat16 Bs[64 * 256];
    const int t = threadIdx.x, lane = t & 63, wvid = t >> 6;
    const int l15 = lane & 15, l4 = lane >> 4;
    const int m0 = blockIdx.x * 64;
    const int nb0 = blockIdx.y * 64;
    const int nc = nb0 + wvid * 16 + l15;
    const int lrow = lane >> 5, lcg = lane & 31;

    for (int rep = 0; rep < REP; ++rep) {
#pragma unroll
        for (int j = 0; j < 8; j++) {
            const int r0 = j * 8 + wvid * 2;
            const int row = r0 + lrow;
            const int cgs = (lcg ^ (row & 7)) & 31;
            gl16(ao + (((size_t)(m0 + row)) << 8) + cgs * 8, (char*)As + r0 * 512);
            gl16(WT + (((size_t)(768 + nb0 + row)) << 8) + cgs * 8, (char*)Bs + r0 * 512);
        }
        __syncthreads();

        f32x4 acc[4] = {{0.f,0.f,0.f,0.f},{0.f,0.f,0.f,0.f},{0.f,0.f,0.f,0.f},{0.f,0.f,0.f,0.f}};
#pragma unroll
        for (int kk = 0; kk < 8; kk++) {
            const int colg = kk * 4 + l4;
            U16B bw; bw.u = *(const uint4*)&Bs[lds_addr(wvid * 16 + l15, colg)];
#pragma unroll
            for (int mt = 0; mt < 4; mt++) {
                U16B ax; ax.u = *(const uint4*)&As[lds_addr(mt * 16 + l15, colg)];
                acc[mt] = __builtin_amdgcn_mfma_f32_16x16x32_bf16(ax.s8, bw.s8, acc[mt], 0, 0, 0);
            }
        }

        const float bb = bias[nc];
#pragma unroll
        for (int mt = 0; mt < 4; mt++)
#pragma unroll
            for (int r = 0; r < 4; r++) {
                int tok = m0 + mt * 16 + l4 * 4 + r;
                out[(size_t)tok * 256 + nc] = acc[mt][r] + bb;
            }
        __syncthreads();
    }
}

extern "C" void kernel_launch(void* const* d_in, const int* in_sizes, int n_in,
                              void* d_out, int out_size, void* d_ws, size_t ws_size,
                              hipStream_t stream) {
    const float* x      = (const float*)d_in[0];
    const float* Wqk    = (const float*)d_in[1];
    const float* Wv     = (const float*)d_in[2];
    const float* Wproj  = (const float*)d_in[3];
    const float* bproj  = (const float*)d_in[4];
    const float* Wpos   = (const float*)d_in[5];
    const float* bpos   = (const float*)d_in[6];
    const float* gating = (const float*)d_in[7];
    float* out = (float*)d_out;

    const size_t nElem = (size_t)BATCH * NP * DIM;  // 1,048,576
    char* w = (char*)d_ws;
    __hip_bfloat16* WT = (__hip_bfloat16*)w;        // 512KB
    __hip_bfloat16* qT = WT + 262144;
    __hip_bfloat16* k  = qT + nElem;
    __hip_bfloat16* vT = k + nElem;
    __hip_bfloat16* ao = vT + nElem;
    __hip_bfloat16* xb = ao + nElem;                // total 10.5MB

    prep_kernel<<<128, 256, 0, stream>>>(Wqk, Wv, Wproj, x, WT, xb);
    qkv_mfma<<<dim3(64, 12), 256, 0, stream>>>(xb, WT, qT, k, vT);
    attn_kernel<<<BATCH * NH * (NP / 64), 512, 0, stream>>>(qT, k, vT, Wpos, bpos, gating, ao);
    proj_mfma<<<dim3(64, 4), 256, 0, stream>>>(ao, WT, bproj, out);
}

// Round 5
// 189.886 us; speedup vs baseline: 3.1752x; 3.1752x over previous
//
#include <hip/hip_runtime.h>
#include <hip/hip_bf16.h>
#include <hip/hip_fp16.h>

#define DIM 256
#define NP 2048
#define NH 8
#define BATCH 2
#define DH 32

typedef __attribute__((ext_vector_type(8))) short bshort8;
typedef __attribute__((ext_vector_type(4))) short bshort4;
typedef __attribute__((ext_vector_type(4))) float f32x4;

#define LOG2E 1.44269504f
// (Dh^-0.5) * log2(e), folded into WT rows 0..255 (W_q) at prep time
#define QSCALE (0.17677669529663687f * LOG2E)

union U16B { uint4 u; bshort8 s8; bshort4 s4x[2]; __hip_bfloat16 h[8]; };
union U8B  { uint2 u; bshort4 s4; __hip_bfloat16 h[4]; };

__device__ __forceinline__ float fexp2(float x) { return __builtin_amdgcn_exp2f(x); }
// pack two fp32 -> two bf16 (truncation) in one v_perm
__device__ __forceinline__ unsigned packbf(float hi, float lo) {
    return __builtin_amdgcn_perm(__float_as_uint(hi), __float_as_uint(lo), 0x07060302u);
}
// async global->LDS, 16B per lane. LDS dest = wave-uniform base + lane*16.
__device__ __forceinline__ void gl16(const void* g, void* l) {
    __builtin_amdgcn_global_load_lds(
        (const __attribute__((address_space(1))) void*)g,
        (__attribute__((address_space(3))) void*)l, 16, 0, 0);
}
// LDS tile addressing: 64 rows x 256 elems, XOR-swizzled 16B granules.
__device__ __forceinline__ int lds_addr(int row, int colg) {
    return row * 256 + (((colg ^ (row & 7)) & 31) << 3);
}

// ============ kernel 0: prep — W transpose -> bf16 WT[1024][256]; x -> bf16 ==
__global__ __launch_bounds__(256) void prep_kernel(
    const float* __restrict__ Wqk,
    const float* __restrict__ Wv,
    const float* __restrict__ Wproj,
    const float* __restrict__ x,
    __hip_bfloat16* __restrict__ WT,
    __hip_bfloat16* __restrict__ xb) {
    const int t = threadIdx.x;
    const int blk = blockIdx.x;
    if (blk >= 64) {
        const int base = (blk - 64) * 256 + t;
#pragma unroll
        for (int i = 0; i < 16; i++) {
            const int idx = base + i * 16384;
            float4 f = *(const float4*)(x + (size_t)idx * 4);
            U8B a;
            a.h[0] = __float2bfloat16(f.x); a.h[1] = __float2bfloat16(f.y);
            a.h[2] = __float2bfloat16(f.z); a.h[3] = __float2bfloat16(f.w);
            *(uint2*)(xb + (size_t)idx * 4) = a.u;
        }
        return;
    }
    __shared__ float ts[64][65];
    const int ct = blk >> 2, k0 = (blk & 3) * 64;
    const int c0 = ct * 64;
    const float* src; int ldw, cs0; float scl = 1.0f;
    if (ct < 8)       { src = Wqk;   ldw = 512; cs0 = c0;      if (ct < 4) scl = QSCALE; }
    else if (ct < 12) { src = Wv;    ldw = 256; cs0 = c0 - 512; }
    else              { src = Wproj; ldw = 256; cs0 = c0 - 768; }
    const int cc = t & 63, tq = t >> 6;
#pragma unroll
    for (int j = 0; j < 16; j++) {
        int kk = tq * 16 + j;
        ts[kk][cc] = src[(size_t)(k0 + kk) * ldw + cs0 + cc];
    }
    __syncthreads();
    const int kk2 = t & 63;
#pragma unroll
    for (int j = 0; j < 16; j++) {
        int cc2 = tq * 16 + j;
        WT[(size_t)(c0 + cc2) * 256 + k0 + kk2] = __float2bfloat16(ts[kk2][cc2] * scl);
    }
}

// ============ kernel 1: QKV projection — global_load_lds staged MFMA GEMM ===
__global__ __launch_bounds__(256) void qkv_mfma(
    const __hip_bfloat16* __restrict__ xb,
    const __hip_bfloat16* __restrict__ WT,
    __hip_bfloat16* __restrict__ qT,
    __hip_bfloat16* __restrict__ k,
    __hip_bfloat16* __restrict__ vT) {
    __shared__ __align__(16) __hip_bfloat16 As[64 * 256];
    __shared__ __align__(16) __hip_bfloat16 Bs[64 * 256];
    const int t = threadIdx.x, lane = t & 63, wvid = t >> 6;
    const int l15 = lane & 15, l4 = lane >> 4;
    const int m0 = blockIdx.x * 64;
    const int nb0 = blockIdx.y * 64;
    const int nc = nb0 + wvid * 16 + l15;
    const int lrow = lane >> 5, lcg = lane & 31;

#pragma unroll
    for (int j = 0; j < 8; j++) {
        const int r0 = j * 8 + wvid * 2;
        const int row = r0 + lrow;
        const int cgs = (lcg ^ (row & 7)) & 31;
        gl16(xb + (((size_t)(m0 + row)) << 8) + cgs * 8, (char*)As + r0 * 512);
        gl16(WT + (((size_t)(nb0 + row)) << 8) + cgs * 8, (char*)Bs + r0 * 512);
    }
    __syncthreads();

    f32x4 acc[4] = {{0.f,0.f,0.f,0.f},{0.f,0.f,0.f,0.f},{0.f,0.f,0.f,0.f},{0.f,0.f,0.f,0.f}};
#pragma unroll
    for (int kk = 0; kk < 8; kk++) {
        const int colg = kk * 4 + l4;
        U16B bw; bw.u = *(const uint4*)&Bs[lds_addr(wvid * 16 + l15, colg)];
#pragma unroll
        for (int mt = 0; mt < 4; mt++) {
            U16B ax; ax.u = *(const uint4*)&As[lds_addr(mt * 16 + l15, colg)];
            acc[mt] = __builtin_amdgcn_mfma_f32_16x16x32_bf16(ax.s8, bw.s8, acc[mt], 0, 0, 0);
        }
    }

    if (nb0 < 256) {             // qT[(b*256+c)][token], 8B stores (QSCALE in WT)
        const int b = m0 >> 11;
#pragma unroll
        for (int mt = 0; mt < 4; mt++) {
            int tokn = (m0 & (NP - 1)) + mt * 16 + l4 * 4;
            U8B vv;
#pragma unroll
            for (int r = 0; r < 4; r++) vv.h[r] = __float2bfloat16(acc[mt][r]);
            *(uint2*)(qT + (size_t)(b * 256 + nc) * NP + tokn) = vv.u;
        }
    } else if (nb0 < 512) {      // k[bh][n][d] (row layout needed by attn staging)
        const int c = nc - 256, h = c >> 5, d = c & 31;
#pragma unroll
        for (int mt = 0; mt < 4; mt++)
#pragma unroll
            for (int r = 0; r < 4; r++) {
                int tok = m0 + mt * 16 + l4 * 4 + r;
                int b = tok >> 11, n = tok & (NP - 1);
                k[((size_t)(b * NH + h) * NP + n) * DH + d] = __float2bfloat16(acc[mt][r]);
            }
    } else {                     // vT[(b*256+c)][token], 8B stores
        const int c = nc - 512;
        const int b = m0 >> 11;
#pragma unroll
        for (int mt = 0; mt < 4; mt++) {
            int tokn = (m0 & (NP - 1)) + mt * 16 + l4 * 4;
            U8B vv;
#pragma unroll
            for (int r = 0; r < 4; r++) vv.h[r] = __float2bfloat16(acc[mt][r]);
            *(uint2*)(vT + (size_t)(b * 256 + c) * NP + tokn) = vv.u;
        }
    }
}

// ============ kernel 1.5: positional stream — separable geometric scan ======
// pos[n,m] = exp2(a2*(n-m)) for m<=n, exp2(b2*(m-n)) for m>=n (a2=(w0+w1),
// b2=(w1-w0), log2-scaled). Forward/backward first-order recurrences with
// direction-monotone max-shifts (pmF = max(0,a2*n), pmB = max(0,b2*(2047-n)))
// => all multipliers <= 1, no overflow; shifted halves recombined in attn.
// grid 32 = bh(16) x dir(2); 8 segments x 256 steps, carry-combined in LDS.
__global__ __launch_bounds__(512) void pos_scan(
    const __hip_bfloat16* __restrict__ vTg,
    const float* __restrict__ Wpos,
    __half* __restrict__ NF,      // [16][2048][32] fwd F̄        (shift pmF)
    __half* __restrict__ NB,      // [16][2048][32] bwd B̄-scl*V  (shift pmB)
    float* __restrict__ lpF,      // [16][2048] fwd row-sum
    float* __restrict__ lpB) {    // [16][2048] bwd row-sum - scl
    __shared__ float Lc[33][8];
    __shared__ float Cin[33][8];
    const int t = threadIdx.x;
    const int bh = blockIdx.x >> 1, dir = blockIdx.x & 1;
    const int h = bh & (NH - 1), b = bh >> 3;
    const float w0 = Wpos[h] * LOG2E, w1 = Wpos[NH + h] * LOG2E;
    const float rate = dir ? (w1 - w0) : (w0 + w1);
    const float mr = fexp2(fminf(rate, 0.f));      // carry multiplier <= 1
    const float sd = fexp2(-fmaxf(rate, 0.f));     // scl per-step ratio <= 1
    const int seg = t / 33, ch = t % 33;           // ch 32 = denominator chain
    const bool act = (t < 264);
    const int n0 = dir ? (seg * 256 + 255) : (seg * 256);
    const int stp = dir ? -1 : 1;
    const float dist0 = dir ? (float)(2047 - n0) : (float)n0;
    const float scl0 = fexp2(-fmaxf(rate, 0.f) * dist0);
    const __hip_bfloat16* vrow = vTg + ((size_t)(b * 256 + h * 32 + (ch & 31))) * NP;

    // phase A: per-segment local scan (zero carry-in), record carry-out
    if (act) {
        float F = 0.f, scl = scl0;
        int n = n0;
        for (int i = 0; i < 256; ++i, n += stp) {
            float V = (ch < 32) ? __bfloat162float(vrow[n]) : 1.0f;
            F = fmaf(mr, F, scl * V);
            scl *= sd;
        }
        Lc[ch][seg] = F;
    }
    __syncthreads();
    // phase B: resolve segment carry-ins (A_s = mr^256, exact since mr const)
    if (t < 33) {
        const float A = fexp2(fminf(rate, 0.f) * 256.f);
        float C = 0.f;
        for (int s = 0; s < 8; ++s) {
            const int ss = dir ? (7 - s) : s;
            Cin[t][ss] = C;
            C = fmaf(A, C, Lc[t][ss]);
        }
    }
    __syncthreads();
    // phase C: re-scan with carries, write outputs
    if (act) {
        float Fc = Cin[ch][seg], scl = scl0;
        int n = n0;
        __half* nout = dir ? NB : NF;
        float* lout = dir ? lpB : lpF;
        for (int i = 0; i < 256; ++i, n += stp) {
            if (ch < 32) {
                float V = __bfloat162float(vrow[n]);
                float tt = scl * V;
                Fc = fmaf(mr, Fc, tt);
                float outv = dir ? (Fc - tt) : Fc;   // bwd excludes diagonal
                nout[((size_t)bh * NP + n) * 32 + ch] = __float2half(outv);
            } else {
                Fc = fmaf(mr, Fc, scl);
                float outv = dir ? (Fc - scl) : Fc;
                lout[(size_t)bh * NP + n] = outv;
            }
            scl *= sd;
        }
    }
}

// ============ kernel 2: attention — content stream only (pos via scan) ======
// grid 512 = bh(16) x qb(32 of 64q). 512 thr / 8 waves: qt = wv&3, kh = wv>>2.
__global__ __launch_bounds__(512, 4) void attn_kernel(
    const __hip_bfloat16* __restrict__ qg,   // qT[bh*32+d][n]
    const __hip_bfloat16* __restrict__ kg,
    const __hip_bfloat16* __restrict__ vTg,
    const float* __restrict__ Wpos,
    const float* __restrict__ gating,
    const __half* __restrict__ NF,
    const __half* __restrict__ NB,
    const float* __restrict__ lpF,
    const float* __restrict__ lpB,
    __hip_bfloat16* __restrict__ ao) {
    __shared__ __align__(16) __hip_bfloat16 Kt[2][2][64][40];  // [kh][buf][key][dh pad40]
    __shared__ __align__(16) __hip_bfloat16 Vt[2][2][32][72];  // [kh][buf][d][key perm pad72]
    __shared__ float cmb[4][32][16];   // [qt][d][q] upper-half partial O (content)
    __shared__ float cls[4][16];       // [qt][q]    upper-half partial sums

    const int t = threadIdx.x;
    const int lane = t & 63, wvid = t >> 6;
    const int l15 = lane & 15, l4 = lane >> 4;
    const int qt = wvid & 3, kh = wvid >> 2;
    const int bh = blockIdx.x >> 5, qb = blockIdx.x & 31;
    const int h = bh & (NH - 1), b = bh >> 3;
    const int q0 = qb * 64 + qt * 16;
    const int myq = q0 + l15;

    const int st_ = t & 255;
    const int kstart = kh * 1024;
    const __hip_bfloat16* kptr = kg + (size_t)bh * NP * DH + (size_t)(kstart + (st_ >> 2)) * DH + (st_ & 3) * 8;
    const __hip_bfloat16* vptr = vTg + ((size_t)bh * DH + (st_ >> 3)) * NP + kstart + (st_ & 7) * 8;

    // permuted V staging addresses (c = s*8+e -> c' = l4(c)*16 + kt(c)*4 + j(c))
    const int vd = st_ >> 3, vs = st_ & 7;
    const int vc0 = ((2 * vs) & 3) * 16 + (vs >> 1) * 4;
    const int vc1 = ((2 * vs + 1) & 3) * 16 + (vs >> 1) * 4;

    uint4 kreg = *(const uint4*)kptr;
    uint4 vreg = *(const uint4*)vptr;
    *(uint4*)&Kt[kh][0][st_ >> 2][(st_ & 3) * 8] = kreg;
    *(uint2*)&Vt[kh][0][vd][vc0] = make_uint2(vreg.x, vreg.y);
    *(uint2*)&Vt[kh][0][vd][vc1] = make_uint2(vreg.z, vreg.w);

    const float w0 = Wpos[h] * LOG2E;
    const float w1 = Wpos[NH + h] * LOG2E;
    const float g = 1.0f / (1.0f + __expf(-gating[h]));
    const float nf = (float)myq;

    U16B qv;
#pragma unroll
    for (int j = 0; j < 8; j++)
        qv.h[j] = qg[((size_t)bh * DH + l4 * 8 + j) * NP + myq];

    __syncthreads();

    f32x4 os0 = {0.f,0.f,0.f,0.f}, os1 = {0.f,0.f,0.f,0.f};
    float ls = 0.f;

    for (int it = 0; it < 16; ++it) {
        const int cur = it & 1, nxt = cur ^ 1;

        if (it < 15) {
            kreg = *(const uint4*)(kptr + (size_t)(it + 1) * 64 * DH);
            vreg = *(const uint4*)(vptr + (it + 1) * 64);
        }

        f32x4 st4[4];
#pragma unroll
        for (int kt = 0; kt < 4; kt++) {
            U16B kf; kf.u = *(const uint4*)&Kt[kh][cur][kt * 16 + l15][l4 * 8];
            st4[kt] = __builtin_amdgcn_mfma_f32_16x16x32_bf16(
                kf.s8, qv.s8, (f32x4){0.f,0.f,0.f,0.f}, 0, 0, 0);
        }

        // V fragments: 4x b128 reads thanks to column permutation
        U16B va0, va1, vb0, vb1;
        {
            const __hip_bfloat16* v0 = &Vt[kh][cur][l15][l4 * 16];
            const __hip_bfloat16* v1 = &Vt[kh][cur][16 + l15][l4 * 16];
            va0.u = *(const uint4*)v0;
            va1.u = *(const uint4*)(v0 + 8);
            vb0.u = *(const uint4*)v1;
            vb1.u = *(const uint4*)(v1 + 8);
        }

#pragma unroll
        for (int kt = 0; kt < 4; kt++) {
            const bshort4 fa = (kt < 2) ? va0.s4x[kt & 1] : va1.s4x[kt & 1];
            const bshort4 fb = (kt < 2) ? vb0.s4x[kt & 1] : vb1.s4x[kt & 1];
            float es0 = fexp2(st4[kt][0]), es1 = fexp2(st4[kt][1]);
            float es2 = fexp2(st4[kt][2]), es3 = fexp2(st4[kt][3]);
            ls += (es0 + es1) + (es2 + es3);
            U8B pc;
            pc.u.x = packbf(es1, es0); pc.u.y = packbf(es3, es2);
            os0 = __builtin_amdgcn_mfma_f32_16x16x16bf16_1k(fa, pc.s4, os0, 0, 0, 0);
            os1 = __builtin_amdgcn_mfma_f32_16x16x16bf16_1k(fb, pc.s4, os1, 0, 0, 0);
        }

        if (it < 15) {
            *(uint4*)&Kt[kh][nxt][st_ >> 2][(st_ & 3) * 8] = kreg;
            *(uint2*)&Vt[kh][nxt][vd][vc0] = make_uint2(vreg.x, vreg.y);
            *(uint2*)&Vt[kh][nxt][vd][vc1] = make_uint2(vreg.z, vreg.w);
        }
        __syncthreads();
    }

    ls += __shfl_xor(ls, 16, 64); ls += __shfl_xor(ls, 32, 64);

    if (kh == 1) {
#pragma unroll
        for (int r = 0; r < 4; r++) {
            cmb[qt][l4 * 4 + r][l15]      = os0[r];
            cmb[qt][16 + l4 * 4 + r][l15] = os1[r];
        }
        if (l4 == 0) cls[qt][l15] = ls;
    }
    __syncthreads();
    if (kh == 0) {
        ls += cls[qt][l15];
        const float cs = (1.0f - g) / ls;
        // recombine the two shifted positional halves at the common row shift
        const float pmF = fmaxf(0.f, (w0 + w1) * nf);
        const float pmB = fmaxf(0.f, (w1 - w0) * (2047.f - nf));
        const float pm  = fmaxf(pmF, pmB);
        const float eF = fexp2(pmF - pm);
        const float eB = fexp2(pmB - pm);
        const size_t lpi = (size_t)bh * NP + myq;
        const float lpv = eF * lpF[lpi] + eB * lpB[lpi];
        const float cp = g / lpv;
        const __half* nfp = NF + lpi * 32 + l4 * 4;
        const __half* nbp = NB + lpi * 32 + l4 * 4;
        const size_t orow = ((size_t)b * NP + myq) * DIM + h * DH;
        U8B o0, o1;
#pragma unroll
        for (int r = 0; r < 4; r++) {
            float p0 = eF * __half2float(nfp[r])      + eB * __half2float(nbp[r]);
            float p1 = eF * __half2float(nfp[16 + r]) + eB * __half2float(nbp[16 + r]);
            o0.h[r] = __float2bfloat16(cs * (os0[r] + cmb[qt][l4 * 4 + r][l15]) + cp * p0);
            o1.h[r] = __float2bfloat16(cs * (os1[r] + cmb[qt][16 + l4 * 4 + r][l15]) + cp * p1);
        }
        *(uint2*)(ao + orow + l4 * 4)      = o0.u;
        *(uint2*)(ao + orow + 16 + l4 * 4) = o1.u;
    }
}

// ============ kernel 3: output projection — global_load_lds staged GEMM =====
__global__ __launch_bounds__(256) void proj_mfma(
    const __hip_bfloat16* __restrict__ ao,
    const __hip_bfloat16* __restrict__ WT,
    const float* __restrict__ bias,
    float* __restrict__ out) {
    __shared__ __align__(16) __hip_bfloat16 As[64 * 256];
    __shared__ __align__(16) __hip_bfloat16 Bs[64 * 256];
    const int t = threadIdx.x, lane = t & 63, wvid = t >> 6;
    const int l15 = lane & 15, l4 = lane >> 4;
    const int m0 = blockIdx.x * 64;
    const int nb0 = blockIdx.y * 64;
    const int nc = nb0 + wvid * 16 + l15;
    const int lrow = lane >> 5, lcg = lane & 31;

#pragma unroll
    for (int j = 0; j < 8; j++) {
        const int r0 = j * 8 + wvid * 2;
        const int row = r0 + lrow;
        const int cgs = (lcg ^ (row & 7)) & 31;
        gl16(ao + (((size_t)(m0 + row)) << 8) + cgs * 8, (char*)As + r0 * 512);
        gl16(WT + (((size_t)(768 + nb0 + row)) << 8) + cgs * 8, (char*)Bs + r0 * 512);
    }
    __syncthreads();

    f32x4 acc[4] = {{0.f,0.f,0.f,0.f},{0.f,0.f,0.f,0.f},{0.f,0.f,0.f,0.f},{0.f,0.f,0.f,0.f}};
#pragma unroll
    for (int kk = 0; kk < 8; kk++) {
        const int colg = kk * 4 + l4;
        U16B bw; bw.u = *(const uint4*)&Bs[lds_addr(wvid * 16 + l15, colg)];
#pragma unroll
        for (int mt = 0; mt < 4; mt++) {
            U16B ax; ax.u = *(const uint4*)&As[lds_addr(mt * 16 + l15, colg)];
            acc[mt] = __builtin_amdgcn_mfma_f32_16x16x32_bf16(ax.s8, bw.s8, acc[mt], 0, 0, 0);
        }
    }

    const float bb = bias[nc];
#pragma unroll
    for (int mt = 0; mt < 4; mt++)
#pragma unroll
        for (int r = 0; r < 4; r++) {
            int tok = m0 + mt * 16 + l4 * 4 + r;
            out[(size_t)tok * 256 + nc] = acc[mt][r] + bb;
        }
}

extern "C" void kernel_launch(void* const* d_in, const int* in_sizes, int n_in,
                              void* d_out, int out_size, void* d_ws, size_t ws_size,
                              hipStream_t stream) {
    const float* x      = (const float*)d_in[0];
    const float* Wqk    = (const float*)d_in[1];
    const float* Wv     = (const float*)d_in[2];
    const float* Wproj  = (const float*)d_in[3];
    const float* bproj  = (const float*)d_in[4];
    const float* Wpos   = (const float*)d_in[5];
    const float* gating = (const float*)d_in[7];
    float* out = (float*)d_out;

    char* w = (char*)d_ws;
    __hip_bfloat16* WT = (__hip_bfloat16*)w;        // 0.5 MB
    __hip_bfloat16* qT = WT + 262144;               // 2 MB
    __hip_bfloat16* k  = qT + 1048576;              // 2 MB
    __hip_bfloat16* vT = k  + 1048576;              // 2 MB
    __hip_bfloat16* ao = vT + 1048576;              // 2 MB
    __hip_bfloat16* xb = ao + 1048576;              // 2 MB  (ends 11,010,048 B)
    __half* NF = (__half*)(w + 11010048);           // 2 MB
    __half* NB = (__half*)(w + 13107200);           // 2 MB
    float* lpF = (float*)(w + 15204352);            // 128 KB
    float* lpB = (float*)(w + 15335424);            // 128 KB (ends ~14.75 MB)

    prep_kernel<<<128, 256, 0, stream>>>(Wqk, Wv, Wproj, x, WT, xb);
    qkv_mfma<<<dim3(64, 12), 256, 0, stream>>>(xb, WT, qT, k, vT);
    pos_scan<<<32, 512, 0, stream>>>(vT, Wpos, NF, NB, lpF, lpB);
    attn_kernel<<<BATCH * NH * (NP / 64), 512, 0, stream>>>(qT, k, vT, Wpos, gating,
                                                            NF, NB, lpF, lpB, ao);
    proj_mfma<<<dim3(64, 4), 256, 0, stream>>>(ao, WT, bproj, out);
}

// Round 6
// 123.118 us; speedup vs baseline: 4.8972x; 1.5423x over previous
//
#include <hip/hip_runtime.h>
#include <hip/hip_bf16.h>
#include <hip/hip_fp16.h>

#define DIM 256
#define NP 2048
#define NH 8
#define BATCH 2
#define DH 32

typedef __attribute__((ext_vector_type(8))) short bshort8;
typedef __attribute__((ext_vector_type(4))) short bshort4;
typedef __attribute__((ext_vector_type(4))) float f32x4;

#define LOG2E 1.44269504f
// (Dh^-0.5) * log2(e), folded into WT rows 0..255 (W_q) at prep time
#define QSCALE (0.17677669529663687f * LOG2E)

union U16B { uint4 u; bshort8 s8; bshort4 s4x[2]; __hip_bfloat16 h[8]; };
union U8B  { uint2 u; bshort4 s4; __hip_bfloat16 h[4]; };

__device__ __forceinline__ float fexp2(float x) { return __builtin_amdgcn_exp2f(x); }
// pack two fp32 -> two bf16 (truncation) in one v_perm
__device__ __forceinline__ unsigned packbf(float hi, float lo) {
    return __builtin_amdgcn_perm(__float_as_uint(hi), __float_as_uint(lo), 0x07060302u);
}
// async global->LDS, 16B per lane. LDS dest = wave-uniform base + lane*16.
__device__ __forceinline__ void gl16(const void* g, void* l) {
    __builtin_amdgcn_global_load_lds(
        (const __attribute__((address_space(1))) void*)g,
        (__attribute__((address_space(3))) void*)l, 16, 0, 0);
}
// LDS tile addressing: 64 rows x 256 elems, XOR-swizzled 16B granules.
__device__ __forceinline__ int lds_addr(int row, int colg) {
    return row * 256 + (((colg ^ (row & 7)) & 31) << 3);
}

// ============ kernel 0: prep — W transpose -> bf16 WT[1024][256]; x -> bf16 ==
__global__ __launch_bounds__(256) void prep_kernel(
    const float* __restrict__ Wqk,
    const float* __restrict__ Wv,
    const float* __restrict__ Wproj,
    const float* __restrict__ x,
    __hip_bfloat16* __restrict__ WT,
    __hip_bfloat16* __restrict__ xb) {
    const int t = threadIdx.x;
    const int blk = blockIdx.x;
    if (blk >= 64) {
        const int base = (blk - 64) * 256 + t;
#pragma unroll
        for (int i = 0; i < 16; i++) {
            const int idx = base + i * 16384;
            float4 f = *(const float4*)(x + (size_t)idx * 4);
            U8B a;
            a.h[0] = __float2bfloat16(f.x); a.h[1] = __float2bfloat16(f.y);
            a.h[2] = __float2bfloat16(f.z); a.h[3] = __float2bfloat16(f.w);
            *(uint2*)(xb + (size_t)idx * 4) = a.u;
        }
        return;
    }
    __shared__ float ts[64][65];
    const int ct = blk >> 2, k0 = (blk & 3) * 64;
    const int c0 = ct * 64;
    const float* src; int ldw, cs0; float scl = 1.0f;
    if (ct < 8)       { src = Wqk;   ldw = 512; cs0 = c0;      if (ct < 4) scl = QSCALE; }
    else if (ct < 12) { src = Wv;    ldw = 256; cs0 = c0 - 512; }
    else              { src = Wproj; ldw = 256; cs0 = c0 - 768; }
    const int cc = t & 63, tq = t >> 6;
#pragma unroll
    for (int j = 0; j < 16; j++) {
        int kk = tq * 16 + j;
        ts[kk][cc] = src[(size_t)(k0 + kk) * ldw + cs0 + cc];
    }
    __syncthreads();
    const int kk2 = t & 63;
#pragma unroll
    for (int j = 0; j < 16; j++) {
        int cc2 = tq * 16 + j;
        WT[(size_t)(c0 + cc2) * 256 + k0 + kk2] = __float2bfloat16(ts[kk2][cc2] * scl);
    }
}

// ============ kernel 1: QKV projection — global_load_lds staged MFMA GEMM ===
__global__ __launch_bounds__(256) void qkv_mfma(
    const __hip_bfloat16* __restrict__ xb,
    const __hip_bfloat16* __restrict__ WT,
    __hip_bfloat16* __restrict__ qT,
    __hip_bfloat16* __restrict__ k,
    __hip_bfloat16* __restrict__ vT) {
    __shared__ __align__(16) __hip_bfloat16 As[64 * 256];
    __shared__ __align__(16) __hip_bfloat16 Bs[64 * 256];
    const int t = threadIdx.x, lane = t & 63, wvid = t >> 6;
    const int l15 = lane & 15, l4 = lane >> 4;
    const int m0 = blockIdx.x * 64;
    const int nb0 = blockIdx.y * 64;
    const int nc = nb0 + wvid * 16 + l15;
    const int lrow = lane >> 5, lcg = lane & 31;

#pragma unroll
    for (int j = 0; j < 8; j++) {
        const int r0 = j * 8 + wvid * 2;
        const int row = r0 + lrow;
        const int cgs = (lcg ^ (row & 7)) & 31;
        gl16(xb + (((size_t)(m0 + row)) << 8) + cgs * 8, (char*)As + r0 * 512);
        gl16(WT + (((size_t)(nb0 + row)) << 8) + cgs * 8, (char*)Bs + r0 * 512);
    }
    __syncthreads();

    f32x4 acc[4] = {{0.f,0.f,0.f,0.f},{0.f,0.f,0.f,0.f},{0.f,0.f,0.f,0.f},{0.f,0.f,0.f,0.f}};
#pragma unroll
    for (int kk = 0; kk < 8; kk++) {
        const int colg = kk * 4 + l4;
        U16B bw; bw.u = *(const uint4*)&Bs[lds_addr(wvid * 16 + l15, colg)];
#pragma unroll
        for (int mt = 0; mt < 4; mt++) {
            U16B ax; ax.u = *(const uint4*)&As[lds_addr(mt * 16 + l15, colg)];
            acc[mt] = __builtin_amdgcn_mfma_f32_16x16x32_bf16(ax.s8, bw.s8, acc[mt], 0, 0, 0);
        }
    }

    if (nb0 < 256) {             // qT[(b*256+c)][token], 8B stores (QSCALE in WT)
        const int b = m0 >> 11;
#pragma unroll
        for (int mt = 0; mt < 4; mt++) {
            int tokn = (m0 & (NP - 1)) + mt * 16 + l4 * 4;
            U8B vv;
#pragma unroll
            for (int r = 0; r < 4; r++) vv.h[r] = __float2bfloat16(acc[mt][r]);
            *(uint2*)(qT + (size_t)(b * 256 + nc) * NP + tokn) = vv.u;
        }
    } else if (nb0 < 512) {      // k[bh][n][d] (row layout needed by attn staging)
        const int c = nc - 256, h = c >> 5, d = c & 31;
#pragma unroll
        for (int mt = 0; mt < 4; mt++)
#pragma unroll
            for (int r = 0; r < 4; r++) {
                int tok = m0 + mt * 16 + l4 * 4 + r;
                int b = tok >> 11, n = tok & (NP - 1);
                k[((size_t)(b * NH + h) * NP + n) * DH + d] = __float2bfloat16(acc[mt][r]);
            }
    } else {                     // vT[(b*256+c)][token], 8B stores
        const int c = nc - 512;
        const int b = m0 >> 11;
#pragma unroll
        for (int mt = 0; mt < 4; mt++) {
            int tokn = (m0 & (NP - 1)) + mt * 16 + l4 * 4;
            U8B vv;
#pragma unroll
            for (int r = 0; r < 4; r++) vv.h[r] = __float2bfloat16(acc[mt][r]);
            *(uint2*)(vT + (size_t)(b * 256 + c) * NP + tokn) = vv.u;
        }
    }
}

// ============ kernel 1.5: positional stream — separable geometric scan ======
// pos[n,m] = exp2(a2*(n-m)) for m<=n, exp2(b2*(m-n)) for m>=n (a2=(w0+w1),
// b2=(w1-w0), log2-scaled). Forward/backward first-order recurrences with
// direction-monotone max-shifts (pmF = max(0,a2*n), pmB = max(0,b2*(2047-n)))
// => all multipliers <= 1, no overflow; shifted halves recombined in attn.
// V5->V6: vectorized uint4 loads (8 bf16/chunk), chunked decay (sd^j regs),
// unroll-4 chunk loop to keep loads in flight; stores lane-coalesced.
// grid 32 = bh(16) x dir(2). t<256: ch=t&31, seg=t>>5; t in [256,264): den.
__global__ __launch_bounds__(512) void pos_scan(
    const __hip_bfloat16* __restrict__ vTg,
    const float* __restrict__ Wpos,
    __half* __restrict__ NF,      // [16][2048][32] fwd F̄        (shift pmF)
    __half* __restrict__ NB,      // [16][2048][32] bwd B̄-scl*V  (shift pmB)
    float* __restrict__ lpF,      // [16][2048] fwd row-sum
    float* __restrict__ lpB) {    // [16][2048] bwd row-sum - scl
    __shared__ float Lc[40][8];
    __shared__ float Cin[40][8];
    const int t = threadIdx.x;
    const int bh = blockIdx.x >> 1, dir = blockIdx.x & 1;
    const int h = bh & (NH - 1), b = bh >> 3;
    const float w0 = Wpos[h] * LOG2E, w1 = Wpos[NH + h] * LOG2E;
    const float rate = dir ? (w1 - w0) : (w0 + w1);
    const float mr = fexp2(fminf(rate, 0.f));      // carry multiplier <= 1
    const float mrate = fmaxf(rate, 0.f);
    const bool isV = (t < 256);
    const bool isD = (t >= 256 && t < 264);
    const bool act = isV || isD;
    const int ch  = isV ? (t & 31) : 32;
    const int seg = isV ? (t >> 5) : (t - 256);
    const int n0 = dir ? (seg * 256 + 255) : (seg * 256);
    const int stp = dir ? -1 : 1;
    const float dist0 = dir ? (float)(2047 - n0) : (float)n0;
    const float scl0 = fexp2(-mrate * dist0);
    float sdp[8];
#pragma unroll
    for (int j = 0; j < 8; j++) sdp[j] = fexp2(-mrate * (float)j);
    const float sd8 = fexp2(-mrate * 8.f);
    const __hip_bfloat16* vrow = vTg + ((size_t)(b * 256 + h * 32 + (ch & 31))) * NP;

    // phase A: per-segment local scan (zero carry-in), record carry-out
    if (act) {
        float F = 0.f, sclc = scl0;
        int n = n0;
#pragma unroll 4
        for (int c = 0; c < 32; ++c) {
            float Wv[8];
            if (isV) {
                U16B vv; vv.u = *(const uint4*)(vrow + (dir ? n - 7 : n));
#pragma unroll
                for (int j = 0; j < 8; j++)
                    Wv[j] = sdp[j] * __bfloat162float(vv.h[dir ? 7 - j : j]);
            } else {
#pragma unroll
                for (int j = 0; j < 8; j++) Wv[j] = sdp[j];
            }
#pragma unroll
            for (int j = 0; j < 8; j++) F = fmaf(mr, F, sclc * Wv[j]);
            sclc *= sd8;
            n += 8 * stp;
        }
        Lc[ch][seg] = F;
    }
    __syncthreads();
    // phase B: resolve segment carry-ins (A_s = mr^256, exact since mr const)
    if (t < 33) {
        const float A = fexp2(fminf(rate, 0.f) * 256.f);
        float C = 0.f;
        for (int s = 0; s < 8; ++s) {
            const int ss = dir ? (7 - s) : s;
            Cin[t][ss] = C;
            C = fmaf(A, C, Lc[t][ss]);
        }
    }
    __syncthreads();
    // phase C: re-scan with carries, write outputs
    if (act) {
        float Fc = Cin[ch][seg], sclc = scl0;
        int n = n0;
        __half* nout = dir ? NB : NF;
        float* lout = dir ? lpB : lpF;
#pragma unroll 4
        for (int c = 0; c < 32; ++c) {
            if (isV) {
                U16B vv; vv.u = *(const uint4*)(vrow + (dir ? n - 7 : n));
#pragma unroll
                for (int j = 0; j < 8; j++) {
                    float tt = sclc * (sdp[j] * __bfloat162float(vv.h[dir ? 7 - j : j]));
                    Fc = fmaf(mr, Fc, tt);
                    float outv = dir ? (Fc - tt) : Fc;   // bwd excludes diagonal
                    nout[((size_t)bh * NP + n + j * stp) * 32 + ch] = __float2half(outv);
                }
            } else {
#pragma unroll
                for (int j = 0; j < 8; j++) {
                    float tt = sclc * sdp[j];
                    Fc = fmaf(mr, Fc, tt);
                    float outv = dir ? (Fc - tt) : Fc;
                    lout[(size_t)bh * NP + n + j * stp] = outv;
                }
            }
            sclc *= sd8;
            n += 8 * stp;
        }
    }
}

// ============ kernel 2: attention — content stream only (pos via scan) ======
// grid 512 = bh(16) x qb(32 of 64q). 512 thr / 8 waves: qt = wv&3, kh = wv>>2.
__global__ __launch_bounds__(512, 4) void attn_kernel(
    const __hip_bfloat16* __restrict__ qg,   // qT[bh*32+d][n]
    const __hip_bfloat16* __restrict__ kg,
    const __hip_bfloat16* __restrict__ vTg,
    const float* __restrict__ Wpos,
    const float* __restrict__ gating,
    const __half* __restrict__ NF,
    const __half* __restrict__ NB,
    const float* __restrict__ lpF,
    const float* __restrict__ lpB,
    __hip_bfloat16* __restrict__ ao) {
    __shared__ __align__(16) __hip_bfloat16 Kt[2][2][64][40];  // [kh][buf][key][dh pad40]
    __shared__ __align__(16) __hip_bfloat16 Vt[2][2][32][72];  // [kh][buf][d][key perm pad72]
    __shared__ float cmb[4][32][16];   // [qt][d][q] upper-half partial O (content)
    __shared__ float cls[4][16];       // [qt][q]    upper-half partial sums

    const int t = threadIdx.x;
    const int lane = t & 63, wvid = t >> 6;
    const int l15 = lane & 15, l4 = lane >> 4;
    const int qt = wvid & 3, kh = wvid >> 2;
    const int bh = blockIdx.x >> 5, qb = blockIdx.x & 31;
    const int h = bh & (NH - 1), b = bh >> 3;
    const int q0 = qb * 64 + qt * 16;
    const int myq = q0 + l15;

    const int st_ = t & 255;
    const int kstart = kh * 1024;
    const __hip_bfloat16* kptr = kg + (size_t)bh * NP * DH + (size_t)(kstart + (st_ >> 2)) * DH + (st_ & 3) * 8;
    const __hip_bfloat16* vptr = vTg + ((size_t)bh * DH + (st_ >> 3)) * NP + kstart + (st_ & 7) * 8;

    // permuted V staging addresses (c = s*8+e -> c' = l4(c)*16 + kt(c)*4 + j(c))
    const int vd = st_ >> 3, vs = st_ & 7;
    const int vc0 = ((2 * vs) & 3) * 16 + (vs >> 1) * 4;
    const int vc1 = ((2 * vs + 1) & 3) * 16 + (vs >> 1) * 4;

    uint4 kreg = *(const uint4*)kptr;
    uint4 vreg = *(const uint4*)vptr;
    *(uint4*)&Kt[kh][0][st_ >> 2][(st_ & 3) * 8] = kreg;
    *(uint2*)&Vt[kh][0][vd][vc0] = make_uint2(vreg.x, vreg.y);
    *(uint2*)&Vt[kh][0][vd][vc1] = make_uint2(vreg.z, vreg.w);

    const float w0 = Wpos[h] * LOG2E;
    const float w1 = Wpos[NH + h] * LOG2E;
    const float g = 1.0f / (1.0f + __expf(-gating[h]));
    const float nf = (float)myq;

    U16B qv;
#pragma unroll
    for (int j = 0; j < 8; j++)
        qv.h[j] = qg[((size_t)bh * DH + l4 * 8 + j) * NP + myq];

    __syncthreads();

    f32x4 os0 = {0.f,0.f,0.f,0.f}, os1 = {0.f,0.f,0.f,0.f};
    float ls = 0.f;

    for (int it = 0; it < 16; ++it) {
        const int cur = it & 1, nxt = cur ^ 1;

        if (it < 15) {
            kreg = *(const uint4*)(kptr + (size_t)(it + 1) * 64 * DH);
            vreg = *(const uint4*)(vptr + (it + 1) * 64);
        }

        f32x4 st4[4];
#pragma unroll
        for (int kt = 0; kt < 4; kt++) {
            U16B kf; kf.u = *(const uint4*)&Kt[kh][cur][kt * 16 + l15][l4 * 8];
            st4[kt] = __builtin_amdgcn_mfma_f32_16x16x32_bf16(
                kf.s8, qv.s8, (f32x4){0.f,0.f,0.f,0.f}, 0, 0, 0);
        }

        // V fragments: 4x b128 reads thanks to column permutation
        U16B va0, va1, vb0, vb1;
        {
            const __hip_bfloat16* v0 = &Vt[kh][cur][l15][l4 * 16];
            const __hip_bfloat16* v1 = &Vt[kh][cur][16 + l15][l4 * 16];
            va0.u = *(const uint4*)v0;
            va1.u = *(const uint4*)(v0 + 8);
            vb0.u = *(const uint4*)v1;
            vb1.u = *(const uint4*)(v1 + 8);
        }

#pragma unroll
        for (int kt = 0; kt < 4; kt++) {
            const bshort4 fa = (kt < 2) ? va0.s4x[kt & 1] : va1.s4x[kt & 1];
            const bshort4 fb = (kt < 2) ? vb0.s4x[kt & 1] : vb1.s4x[kt & 1];
            float es0 = fexp2(st4[kt][0]), es1 = fexp2(st4[kt][1]);
            float es2 = fexp2(st4[kt][2]), es3 = fexp2(st4[kt][3]);
            ls += (es0 + es1) + (es2 + es3);
            U8B pc;
            pc.u.x = packbf(es1, es0); pc.u.y = packbf(es3, es2);
            os0 = __builtin_amdgcn_mfma_f32_16x16x16bf16_1k(fa, pc.s4, os0, 0, 0, 0);
            os1 = __builtin_amdgcn_mfma_f32_16x16x16bf16_1k(fb, pc.s4, os1, 0, 0, 0);
        }

        if (it < 15) {
            *(uint4*)&Kt[kh][nxt][st_ >> 2][(st_ & 3) * 8] = kreg;
            *(uint2*)&Vt[kh][nxt][vd][vc0] = make_uint2(vreg.x, vreg.y);
            *(uint2*)&Vt[kh][nxt][vd][vc1] = make_uint2(vreg.z, vreg.w);
        }
        __syncthreads();
    }

    ls += __shfl_xor(ls, 16, 64); ls += __shfl_xor(ls, 32, 64);

    if (kh == 1) {
#pragma unroll
        for (int r = 0; r < 4; r++) {
            cmb[qt][l4 * 4 + r][l15]      = os0[r];
            cmb[qt][16 + l4 * 4 + r][l15] = os1[r];
        }
        if (l4 == 0) cls[qt][l15] = ls;
    }
    __syncthreads();
    if (kh == 0) {
        ls += cls[qt][l15];
        const float cs = (1.0f - g) / ls;
        // recombine the two shifted positional halves at the common row shift
        const float pmF = fmaxf(0.f, (w0 + w1) * nf);
        const float pmB = fmaxf(0.f, (w1 - w0) * (2047.f - nf));
        const float pm  = fmaxf(pmF, pmB);
        const float eF = fexp2(pmF - pm);
        const float eB = fexp2(pmB - pm);
        const size_t lpi = (size_t)bh * NP + myq;
        const float lpv = eF * lpF[lpi] + eB * lpB[lpi];
        const float cp = g / lpv;
        const __half* nfp = NF + lpi * 32 + l4 * 4;
        const __half* nbp = NB + lpi * 32 + l4 * 4;
        const size_t orow = ((size_t)b * NP + myq) * DIM + h * DH;
        U8B o0, o1;
#pragma unroll
        for (int r = 0; r < 4; r++) {
            float p0 = eF * __half2float(nfp[r])      + eB * __half2float(nbp[r]);
            float p1 = eF * __half2float(nfp[16 + r]) + eB * __half2float(nbp[16 + r]);
            o0.h[r] = __float2bfloat16(cs * (os0[r] + cmb[qt][l4 * 4 + r][l15]) + cp * p0);
            o1.h[r] = __float2bfloat16(cs * (os1[r] + cmb[qt][16 + l4 * 4 + r][l15]) + cp * p1);
        }
        *(uint2*)(ao + orow + l4 * 4)      = o0.u;
        *(uint2*)(ao + orow + 16 + l4 * 4) = o1.u;
    }
}

// ============ kernel 3: output projection — global_load_lds staged GEMM =====
__global__ __launch_bounds__(256) void proj_mfma(
    const __hip_bfloat16* __restrict__ ao,
    const __hip_bfloat16* __restrict__ WT,
    const float* __restrict__ bias,
    float* __restrict__ out) {
    __shared__ __align__(16) __hip_bfloat16 As[64 * 256];
    __shared__ __align__(16) __hip_bfloat16 Bs[64 * 256];
    const int t = threadIdx.x, lane = t & 63, wvid = t >> 6;
    const int l15 = lane & 15, l4 = lane >> 4;
    const int m0 = blockIdx.x * 64;
    const int nb0 = blockIdx.y * 64;
    const int nc = nb0 + wvid * 16 + l15;
    const int lrow = lane >> 5, lcg = lane & 31;

#pragma unroll
    for (int j = 0; j < 8; j++) {
        const int r0 = j * 8 + wvid * 2;
        const int row = r0 + lrow;
        const int cgs = (lcg ^ (row & 7)) & 31;
        gl16(ao + (((size_t)(m0 + row)) << 8) + cgs * 8, (char*)As + r0 * 512);
        gl16(WT + (((size_t)(768 + nb0 + row)) << 8) + cgs * 8, (char*)Bs + r0 * 512);
    }
    __syncthreads();

    f32x4 acc[4] = {{0.f,0.f,0.f,0.f},{0.f,0.f,0.f,0.f},{0.f,0.f,0.f,0.f},{0.f,0.f,0.f,0.f}};
#pragma unroll
    for (int kk = 0; kk < 8; kk++) {
        const int colg = kk * 4 + l4;
        U16B bw; bw.u = *(const uint4*)&Bs[lds_addr(wvid * 16 + l15, colg)];
#pragma unroll
        for (int mt = 0; mt < 4; mt++) {
            U16B ax; ax.u = *(const uint4*)&As[lds_addr(mt * 16 + l15, colg)];
            acc[mt] = __builtin_amdgcn_mfma_f32_16x16x32_bf16(ax.s8, bw.s8, acc[mt], 0, 0, 0);
        }
    }

    const float bb = bias[nc];
#pragma unroll
    for (int mt = 0; mt < 4; mt++)
#pragma unroll
        for (int r = 0; r < 4; r++) {
            int tok = m0 + mt * 16 + l4 * 4 + r;
            out[(size_t)tok * 256 + nc] = acc[mt][r] + bb;
        }
}

extern "C" void kernel_launch(void* const* d_in, const int* in_sizes, int n_in,
                              void* d_out, int out_size, void* d_ws, size_t ws_size,
                              hipStream_t stream) {
    const float* x      = (const float*)d_in[0];
    const float* Wqk    = (const float*)d_in[1];
    const float* Wv     = (const float*)d_in[2];
    const float* Wproj  = (const float*)d_in[3];
    const float* bproj  = (const float*)d_in[4];
    const float* Wpos   = (const float*)d_in[5];
    const float* gating = (const float*)d_in[7];
    float* out = (float*)d_out;

    char* w = (char*)d_ws;
    __hip_bfloat16* WT = (__hip_bfloat16*)w;        // 0.5 MB
    __hip_bfloat16* qT = WT + 262144;               // 2 MB
    __hip_bfloat16* k  = qT + 1048576;              // 2 MB
    __hip_bfloat16* vT = k  + 1048576;              // 2 MB
    __hip_bfloat16* ao = vT + 1048576;              // 2 MB
    __hip_bfloat16* xb = ao + 1048576;              // 2 MB  (ends 11,010,048 B)
    __half* NF = (__half*)(w + 11010048);           // 2 MB
    __half* NB = (__half*)(w + 13107200);           // 2 MB
    float* lpF = (float*)(w + 15204352);            // 128 KB
    float* lpB = (float*)(w + 15335424);            // 128 KB (ends ~14.75 MB)

    prep_kernel<<<128, 256, 0, stream>>>(Wqk, Wv, Wproj, x, WT, xb);
    qkv_mfma<<<dim3(64, 12), 256, 0, stream>>>(xb, WT, qT, k, vT);
    pos_scan<<<32, 512, 0, stream>>>(vT, Wpos, NF, NB, lpF, lpB);
    attn_kernel<<<BATCH * NH * (NP / 64), 512, 0, stream>>>(qT, k, vT, Wpos, gating,
                                                            NF, NB, lpF, lpB, ao);
    proj_mfma<<<dim3(64, 4), 256, 0, stream>>>(ao, WT, bproj, out);
}